// Round 9
// baseline (7127.328 us; speedup 1.0000x reference)
//
#include <hip/hip_runtime.h>

// Problem constants (B == H == 128, T == 64)
#define TT   64
#define HD   128
#define BB   128
#define RR   4       // batch/LSTM rows per block
#define NB   32      // persistent blocks (fan-in 32)
#define NT   512
#define REP  4       // diagnostic repetitions (REP*TT rounds)

typedef unsigned int u32;
typedef unsigned long long u64;
typedef _Float16 half2v __attribute__((ext_vector_type(2)));

#if defined(__has_builtin)
#  if __has_builtin(__builtin_amdgcn_fdot2)
#    define FDOT2(a,b,c) __builtin_amdgcn_fdot2((a),(b),(c),false)
#  endif
#endif
#ifndef FDOT2
#  define FDOT2(a,b,c) ((c) + (float)(a).x*(float)(b).x + (float)(a).y*(float)(b).y)
#endif

__device__ __forceinline__ float fast_rcp(float x){ return __builtin_amdgcn_rcpf(x); }
__device__ __forceinline__ float fast_tanh(float x){
    float e = __expf(2.f*x);
    return 1.f - 2.f*__builtin_amdgcn_rcpf(e+1.f);
}
__device__ __forceinline__ float fast_sigmoid(float x){
    return __builtin_amdgcn_rcpf(1.f + __expf(-x));
}
__device__ __forceinline__ u32 packh2(float a, float b){
    half2v v; v.x = (_Float16)a; v.y = (_Float16)b;
    return __builtin_bit_cast(u32, v);
}
__device__ __forceinline__ half2v ash2(u32 u){ return __builtin_bit_cast(half2v, u); }

// ---------------- precompute kernels ----------------

// preE2[row][kk] = f16pair{ preE[row][2kk], preE[row][2kk+1] },
// preE[row][k] = b1[k] + sum_j Xe[row][j] * W1[k][256+j]   (row = b*T+t)
__global__ __launch_bounds__(256) void k_pre(const float* __restrict__ Xe,
    const float* __restrict__ W1, const float* __restrict__ b1,
    u32* __restrict__ preE2){
    __shared__ float2 sx2[16*HD];
    __shared__ float  red[512];
    __shared__ float  tmp[256];
    const int tid = threadIdx.x;
    const int k = tid & 127, q = tid >> 7;
    const int r0 = blockIdx.x * 32;
    float wv[64];
    { const float4* wp = (const float4*)(W1 + (size_t)k*384 + 256 + q*64);
      #pragma unroll
      for (int c=0;c<16;c++){ float4 v=wp[c]; wv[4*c]=v.x; wv[4*c+1]=v.y; wv[4*c+2]=v.z; wv[4*c+3]=v.w; } }
    const float b1k = b1[k];
    float* sxf = (float*)sx2;
    for (int i=tid; i<32*HD; i+=256){
        int row = i>>7, m = i&127;
        sxf[((row>>1)*HD + m)*2 + (row&1)] = Xe[(size_t)(r0+row)*HD + m];
    }
    __syncthreads();
    for (int p=0;p<16;p++){
        const float2* xp = sx2 + p*HD + q*64;
        float a0=0.f, a1=0.f;
        #pragma unroll
        for (int i=0;i<64;i++){ float2 xv = xp[i]; a0 += xv.x*wv[i]; a1 += xv.y*wv[i]; }
        red[tid] = a0; red[256+tid] = a1;
        __syncthreads();
        if (tid<128){
            tmp[tid]     = red[tid]     + red[128+tid] + b1k;
            tmp[128+tid] = red[256+tid] + red[384+tid] + b1k;
        }
        __syncthreads();
        if (tid<128){
            int row = tid>>6, kk = tid&63;
            preE2[(size_t)(r0+2*p+row)*64 + kk] = packh2(tmp[row*128+2*kk], tmp[row*128+2*kk+1]);
        }
        __syncthreads();
    }
}

// pack W1[h;cc] -> W1T[i][k] u32 (i = m-pair), Whh -> WhhPT[kk][j] u32
__global__ void k_pack(const float* __restrict__ W1, const float* __restrict__ Whh,
                       u32* __restrict__ W1T, u32* __restrict__ WhhPT){
    int idx = blockIdx.x*blockDim.x + threadIdx.x;
    int stride = gridDim.x*blockDim.x;
    for (int n=idx; n<128*128; n+=stride){
        int k = n>>7, i = n&127;
        float2 v = *(const float2*)(W1 + (size_t)k*384 + 2*i);
        W1T[i*128 + k] = packh2(v.x, v.y);
    }
    for (int n=idx; n<512*64; n+=stride){
        int j = n>>6, kk = n&63;
        float2 v = *(const float2*)(Whh + (size_t)j*HD + 2*kk);
        WhhPT[kk*512 + j] = packh2(v.x, v.y);
    }
}

// xtwT[e][t] = bfc + sum_b Xt[b][t][e] * Wfc[128+b]
__global__ __launch_bounds__(128) void k_xtw(const float* __restrict__ Xt,
    const float* __restrict__ Wfc, const float* __restrict__ bfc,
    float* __restrict__ xtwT){
    const int t = blockIdx.x, e = threadIdx.x;
    float acc = bfc[0];
    #pragma unroll 8
    for (int b=0;b<BB;b++)
        acc += Xt[((size_t)b*TT + t)*HD + e] * Wfc[BB+b];
    xtwT[(size_t)e*TT + t] = acc;
}

#define TRM(u, hl, hh, wl, wh) { half2v v=ash2(u); \
    acc += (wl)*fast_tanh((float)v.x+(hl)); acc += (wh)*fast_tanh((float)v.y+(hh)); }

// ---------------- persistent scan kernel (32 blocks x 4 rows) ----------------
__global__ __launch_bounds__(NT,1) void k_loop(
    const float* __restrict__ Xe, const u32* __restrict__ preE2,
    const u32* __restrict__ W1T, const u32* __restrict__ WhhPT,
    const float* __restrict__ W2, const float* __restrict__ b2,
    const float* __restrict__ Wfc,
    const float* __restrict__ Wih, const float* __restrict__ bih,
    const float* __restrict__ bhh,
    const float* __restrict__ Wfin, const float* __restrict__ bfin,
    const float* __restrict__ xtwT,
    u64* __restrict__ Ptv, float* __restrict__ out)
{
    extern __shared__ u32 dyn[];
    u32* sW1  = dyn;            // [i=128 m-pairs][k=128] = 16384 u32 (64 KB)
    u32* spre = dyn + 16384;    // [r][tp][kk] 4*64*64 u32 (64 KB)
    __shared__ __align__(16) u32 sxT[128*RR];   // [mp][r], uint4 per mp
    __shared__ float sh[RR][HD], scc[RR][HD];
    __shared__ __align__(16) float shW1s[RR][HD];
    __shared__ float sa[RR][TT], sbeta[RR][TT], sctx[RR][HD];
    __shared__ __align__(16) float4 red4[NT];
    __shared__ float sWih[NT], sbihh[NT], sWfin[2*HD], sxtw[RR][TT];
    __shared__ float sy1[RR];

    const int tid = threadIdx.x;
    const int g   = blockIdx.x;

    { const uint4* s1 = (const uint4*)W1T; uint4* d1 = (uint4*)sW1;
      const uint4* s2 = (const uint4*)(preE2 + (size_t)(RR*g)*TT*64);
      uint4* d2 = (uint4*)spre;
      for (int i=tid;i<4096;i+=NT){ d1[i]=s1[i]; d2[i]=s2[i]; } }
    u32 whr[64];
    #pragma unroll
    for (int kk=0;kk<64;kk++) whr[kk] = WhhPT[kk*512 + tid];
    float w2r[16];
    { int kb = (tid&7)*16;
      #pragma unroll
      for (int j=0;j<16;j++) w2r[j] = W2[kb+j]; }
    sWih[tid]  = Wih[tid];
    sbihh[tid] = bih[tid] + bhh[tid];
    if (tid < 2*HD) sWfin[tid] = Wfin[tid];
    if (tid < RR*HD){ int r=tid>>7, u=tid&127; sh[r][u]=0.f; scc[r][u]=0.f; }
    if (tid < RR*TT){ int r=tid>>6, t=tid&63; sxtw[r][t] = xtwT[(size_t)(RR*g+r)*TT + t]; }
    sxT[tid] = 0u;
    float wfc[RR];
    #pragma unroll
    for (int r=0;r<RR;r++) wfc[r] = Wfc[RR*g+r];
    const float b2v = b2[0];
    __syncthreads();

    for (int t=0;t<TT;t++){
        u64* Pcur = Ptv + (size_t)(t&1)*BB*NB;

        // P1: hW1[r][k] = sum_m x_r[m] W1[k][m]
        {
            const int k = tid&127, mq = tid>>7;
            const uint4* xv = (const uint4*)sxT;
            float a0=0,a1=0,a2=0,a3=0;
            #pragma unroll
            for (int i=0;i<32;i++){
                int ip = mq*32+i;
                half2v w = ash2(sW1[ip*128 + k]);
                uint4 x = xv[ip];
                a0 = FDOT2(w, ash2(x.x), a0);
                a1 = FDOT2(w, ash2(x.y), a1);
                a2 = FDOT2(w, ash2(x.z), a2);
                a3 = FDOT2(w, ash2(x.w), a3);
            }
            red4[tid] = make_float4(a0,a1,a2,a3);
        }
        __syncthreads();
        {
            int r = tid>>7, k = tid&127;
            float s = 0.f;
            #pragma unroll
            for (int mq=0;mq<4;mq++){ const float* f=(const float*)&red4[mq*128+k]; s += f[r]; }
            shW1s[r][k] = s;
        }
        __syncthreads();

        // P2: a[r][tp] = b2 + sum_k W2[k] tanh(preE + hW1)
        {
            const int tp = tid>>3, kp = tid&7, kb = kp*16;
            #pragma unroll
            for (int r=0;r<RR;r++){
                const uint4* pp = (const uint4*)(spre + ((r*TT+tp)*64 + kp*8));
                uint4 q0 = pp[0], q1 = pp[1];
                const float4* hw = (const float4*)&shW1s[r][kb];
                float4 h0=hw[0], h1=hw[1], h2=hw[2], h3=hw[3];
                float acc=0.f;
                TRM(q0.x,h0.x,h0.y,w2r[0],w2r[1])  TRM(q0.y,h0.z,h0.w,w2r[2],w2r[3])
                TRM(q0.z,h1.x,h1.y,w2r[4],w2r[5])  TRM(q0.w,h1.z,h1.w,w2r[6],w2r[7])
                TRM(q1.x,h2.x,h2.y,w2r[8],w2r[9])  TRM(q1.y,h2.z,h2.w,w2r[10],w2r[11])
                TRM(q1.z,h3.x,h3.y,w2r[12],w2r[13])TRM(q1.w,h3.z,h3.w,w2r[14],w2r[15])
                acc += __shfl_xor(acc,1); acc += __shfl_xor(acc,2); acc += __shfl_xor(acc,4);
                if (kp==0) sa[r][tp] = acc + b2v;
            }
        }
        __syncthreads();

        // P3: softmax per row (4 waves)
        if (tid < RR*TT){
            int r = tid>>6, l = tid&63;
            float v = sa[r][l], mx=v;
            #pragma unroll
            for (int d=32;d;d>>=1) mx = fmaxf(mx, __shfl_xor(mx,d));
            float e = __expf(v-mx), s=e;
            #pragma unroll
            for (int d=32;d;d>>=1) s += __shfl_xor(s,d);
            sbeta[r][l] = e*fast_rcp(s);
        }
        __syncthreads();

        // P4: ctx partials
        {
            const int e = tid&127, tq = tid>>7;
            float a[RR] = {0,0,0,0};
            #pragma unroll
            for (int r=0;r<RR;r++){
                const float* xr = Xe + ((size_t)(RR*g+r)*TT + tq*16)*HD + e;
                #pragma unroll
                for (int c=0;c<16;c++) a[r] += sbeta[r][tq*16+c]*xr[c*HD];
            }
            red4[tid] = make_float4(a[0],a[1],a[2],a[3]);
        }
        __syncthreads();
        if (tid<HD){
            float4 c0=red4[tid], c1=red4[128+tid], c2=red4[256+tid], c3=red4[384+tid];
            float v0=c0.x+c1.x+c2.x+c3.x, v1=c0.y+c1.y+c2.y+c3.y;
            float v2=c0.z+c1.z+c2.z+c3.z, v3=c0.w+c1.w+c2.w+c3.w;
            sctx[0][tid]=v0; sctx[1][tid]=v1; sctx[2][tid]=v2; sctx[3][tid]=v3;
            float partial = v0*wfc[0]+v1*wfc[1]+v2*wfc[2]+v3*wfc[3];
            u64 pk = ((u64)(u32)(t+1)<<32) | (u64)__float_as_uint(partial);
            __hip_atomic_store(&Pcur[(size_t)tid*NB + g], pk,
                               __ATOMIC_RELAXED, __HIP_MEMORY_SCOPE_AGENT);
        }
        // P5: ghh (register Whh) — hides store flight
        float gj0=0,gj1=0,gj2=0,gj3=0;
        {
            const uint4* xv = (const uint4*)sxT;
            #pragma unroll
            for (int kk=0;kk<64;kk++){
                uint4 x = xv[kk];
                half2v w = ash2(whr[kk]);
                gj0 = FDOT2(w, ash2(x.x), gj0);
                gj1 = FDOT2(w, ash2(x.y), gj1);
                gj2 = FDOT2(w, ash2(x.z), gj2);
                gj3 = FDOT2(w, ash2(x.w), gj3);
            }
        }
        // P5b: poll (waves 0-1)
        if (tid<128){
            const int r = tid>>5, gp = tid&31;
            const u64* slot = &Pcur[(size_t)(RR*g+r)*NB + gp];
            const u32 tag = (u32)(t+1);
            u64 v;
            for(;;){
                v = __hip_atomic_load(slot, __ATOMIC_RELAXED, __HIP_MEMORY_SCOPE_AGENT);
                if (__all((u32)(v>>32)==tag)) break;
            }
            float s = __uint_as_float((u32)v);
            s += __shfl_xor(s,16); s += __shfl_xor(s,8); s += __shfl_xor(s,4);
            s += __shfl_xor(s,2);  s += __shfl_xor(s,1);
            if (gp==0) sy1[r] = s + sxtw[r][t];
        }
        __syncthreads();

        // P6: gates + cell update + f16 repack
        {
            float wij = sWih[tid], bj = sbihh[tid];
            red4[tid] = make_float4(gj0 + sy1[0]*wij + bj, gj1 + sy1[1]*wij + bj,
                                    gj2 + sy1[2]*wij + bj, gj3 + sy1[3]*wij + bj);
        }
        __syncthreads();
        if (tid<HD){
            const int u = tid;
            float4 gi = red4[u], gf = red4[128+u], gg = red4[256+u], go = red4[384+u];
            float h2v[RR], c2v[RR];
            { float c2 = fast_sigmoid(gf.x)*scc[0][u] + fast_sigmoid(gi.x)*fast_tanh(gg.x);
              h2v[0]=fast_sigmoid(go.x)*fast_tanh(c2); c2v[0]=c2; }
            { float c2 = fast_sigmoid(gf.y)*scc[1][u] + fast_sigmoid(gi.y)*fast_tanh(gg.y);
              h2v[1]=fast_sigmoid(go.y)*fast_tanh(c2); c2v[1]=c2; }
            { float c2 = fast_sigmoid(gf.z)*scc[2][u] + fast_sigmoid(gi.z)*fast_tanh(gg.z);
              h2v[2]=fast_sigmoid(go.z)*fast_tanh(c2); c2v[2]=c2; }
            { float c2 = fast_sigmoid(gf.w)*scc[3][u] + fast_sigmoid(gi.w)*fast_tanh(gg.w);
              h2v[3]=fast_sigmoid(go.w)*fast_tanh(c2); c2v[3]=c2; }
            u32 ph[RR], pc[RR];
            #pragma unroll
            for (int r=0;r<RR;r++){
                sh[r][u]=h2v[r]; scc[r][u]=c2v[r];
                float hn = __shfl_xor(h2v[r],1);
                float cn = __shfl_xor(c2v[r],1);
                ph[r] = packh2(h2v[r], hn);
                pc[r] = packh2(c2v[r], cn);
            }
            if (!(u&1)){
                uint4* x4 = (uint4*)sxT;
                x4[u>>1]        = make_uint4(ph[0],ph[1],ph[2],ph[3]);
                x4[64 + (u>>1)] = make_uint4(pc[0],pc[1],pc[2],pc[3]);
            }
        }
        __syncthreads();
    }

    // epilogue
    {
        const int r = tid>>7, u = tid&127;
        float p = sh[r][u]*sWfin[u] + sctx[r][u]*sWfin[HD+u];
        #pragma unroll
        for (int d=32;d;d>>=1) p += __shfl_xor(p,d);
        if ((tid&63)==0) ((float*)red4)[tid>>6] = p;
    }
    __syncthreads();
    if (tid<RR) out[RR*g+tid] = ((float*)red4)[2*tid] + ((float*)red4)[2*tid+1] + bfin[0];
}

// ---------------- diagnostic: compute-only (no exchange) ----------------
__global__ __launch_bounds__(NT,1) void k_diag_comp(
    const float* __restrict__ Xe, const u32* __restrict__ preE2,
    const u32* __restrict__ W1T, const u32* __restrict__ WhhPT,
    const float* __restrict__ W2, const float* __restrict__ b2,
    const float* __restrict__ Wfc,
    const float* __restrict__ Wih, const float* __restrict__ bih,
    const float* __restrict__ bhh, const float* __restrict__ xtwT,
    float* __restrict__ dout)
{
    extern __shared__ u32 dyn[];
    u32* sW1  = dyn;
    u32* spre = dyn + 16384;
    __shared__ __align__(16) u32 sxT[128*RR];
    __shared__ float sh[RR][HD], scc[RR][HD];
    __shared__ __align__(16) float shW1s[RR][HD];
    __shared__ float sa[RR][TT], sbeta[RR][TT], sctx[RR][HD];
    __shared__ __align__(16) float4 red4[NT];
    __shared__ float sWih[NT], sbihh[NT], sxtw[RR][TT];
    __shared__ float sy1[RR];

    const int tid = threadIdx.x;
    const int g   = blockIdx.x;

    { const uint4* s1 = (const uint4*)W1T; uint4* d1 = (uint4*)sW1;
      const uint4* s2 = (const uint4*)(preE2 + (size_t)(RR*g)*TT*64);
      uint4* d2 = (uint4*)spre;
      for (int i=tid;i<4096;i+=NT){ d1[i]=s1[i]; d2[i]=s2[i]; } }
    u32 whr[64];
    #pragma unroll
    for (int kk=0;kk<64;kk++) whr[kk] = WhhPT[kk*512 + tid];
    float w2r[16];
    { int kb = (tid&7)*16;
      #pragma unroll
      for (int j=0;j<16;j++) w2r[j] = W2[kb+j]; }
    sWih[tid]  = Wih[tid];
    sbihh[tid] = bih[tid] + bhh[tid];
    if (tid < RR*HD){ int r=tid>>7, u=tid&127; sh[r][u]=0.f; scc[r][u]=0.f; }
    if (tid < RR*TT){ int r=tid>>6, t=tid&63; sxtw[r][t] = xtwT[(size_t)(RR*g+r)*TT + t]; }
    sxT[tid] = 0u;
    const float b2v = b2[0];
    __syncthreads();

    for (int it=0; it<REP*TT; it++){
        int t = it & 63;
        {
            const int k = tid&127, mq = tid>>7;
            const uint4* xv = (const uint4*)sxT;
            float a0=0,a1=0,a2=0,a3=0;
            #pragma unroll
            for (int i=0;i<32;i++){
                int ip = mq*32+i;
                half2v w = ash2(sW1[ip*128 + k]);
                uint4 x = xv[ip];
                a0 = FDOT2(w, ash2(x.x), a0);
                a1 = FDOT2(w, ash2(x.y), a1);
                a2 = FDOT2(w, ash2(x.z), a2);
                a3 = FDOT2(w, ash2(x.w), a3);
            }
            red4[tid] = make_float4(a0,a1,a2,a3);
        }
        __syncthreads();
        {
            int r = tid>>7, k = tid&127;
            float s = 0.f;
            #pragma unroll
            for (int mq=0;mq<4;mq++){ const float* f=(const float*)&red4[mq*128+k]; s += f[r]; }
            shW1s[r][k] = s;
        }
        __syncthreads();
        {
            const int tp = tid>>3, kp = tid&7, kb = kp*16;
            #pragma unroll
            for (int r=0;r<RR;r++){
                const uint4* pp = (const uint4*)(spre + ((r*TT+tp)*64 + kp*8));
                uint4 q0 = pp[0], q1 = pp[1];
                const float4* hw = (const float4*)&shW1s[r][kb];
                float4 h0=hw[0], h1=hw[1], h2=hw[2], h3=hw[3];
                float acc=0.f;
                TRM(q0.x,h0.x,h0.y,w2r[0],w2r[1])  TRM(q0.y,h0.z,h0.w,w2r[2],w2r[3])
                TRM(q0.z,h1.x,h1.y,w2r[4],w2r[5])  TRM(q0.w,h1.z,h1.w,w2r[6],w2r[7])
                TRM(q1.x,h2.x,h2.y,w2r[8],w2r[9])  TRM(q1.y,h2.z,h2.w,w2r[10],w2r[11])
                TRM(q1.z,h3.x,h3.y,w2r[12],w2r[13])TRM(q1.w,h3.z,h3.w,w2r[14],w2r[15])
                acc += __shfl_xor(acc,1); acc += __shfl_xor(acc,2); acc += __shfl_xor(acc,4);
                if (kp==0) sa[r][tp] = acc + b2v;
            }
        }
        __syncthreads();
        if (tid < RR*TT){
            int r = tid>>6, l = tid&63;
            float v = sa[r][l], mx=v;
            #pragma unroll
            for (int d=32;d;d>>=1) mx = fmaxf(mx, __shfl_xor(mx,d));
            float e = __expf(v-mx), s=e;
            #pragma unroll
            for (int d=32;d;d>>=1) s += __shfl_xor(s,d);
            sbeta[r][l] = e*fast_rcp(s);
        }
        __syncthreads();
        {
            const int e = tid&127, tq = tid>>7;
            float a[RR] = {0,0,0,0};
            #pragma unroll
            for (int r=0;r<RR;r++){
                const float* xr = Xe + ((size_t)(RR*g+r)*TT + tq*16)*HD + e;
                #pragma unroll
                for (int c=0;c<16;c++) a[r] += sbeta[r][tq*16+c]*xr[c*HD];
            }
            red4[tid] = make_float4(a[0],a[1],a[2],a[3]);
        }
        __syncthreads();
        if (tid<HD){
            float4 c0=red4[tid], c1=red4[128+tid], c2=red4[256+tid], c3=red4[384+tid];
            sctx[0][tid]=c0.x+c1.x+c2.x+c3.x; sctx[1][tid]=c0.y+c1.y+c2.y+c3.y;
            sctx[2][tid]=c0.z+c1.z+c2.z+c3.z; sctx[3][tid]=c0.w+c1.w+c2.w+c3.w;
        }
        float gj0=0,gj1=0,gj2=0,gj3=0;
        {
            const uint4* xv = (const uint4*)sxT;
            #pragma unroll
            for (int kk=0;kk<64;kk++){
                uint4 x = xv[kk];
                half2v w = ash2(whr[kk]);
                gj0 = FDOT2(w, ash2(x.x), gj0);
                gj1 = FDOT2(w, ash2(x.y), gj1);
                gj2 = FDOT2(w, ash2(x.z), gj2);
                gj3 = FDOT2(w, ash2(x.w), gj3);
            }
        }
        if (tid<128){   // fake exchange: local dependency only
            const int r = tid>>5, gp = tid&31;
            float s = sctx[r][gp] * 1e-3f;
            s += __shfl_xor(s,16); s += __shfl_xor(s,8); s += __shfl_xor(s,4);
            s += __shfl_xor(s,2);  s += __shfl_xor(s,1);
            if (gp==0) sy1[r] = s + sxtw[r][t];
        }
        __syncthreads();
        {
            float wij = sWih[tid], bj = sbihh[tid];
            red4[tid] = make_float4(gj0 + sy1[0]*wij + bj, gj1 + sy1[1]*wij + bj,
                                    gj2 + sy1[2]*wij + bj, gj3 + sy1[3]*wij + bj);
        }
        __syncthreads();
        if (tid<HD){
            const int u = tid;
            float4 gi = red4[u], gf = red4[128+u], gg = red4[256+u], go = red4[384+u];
            float h2v[RR], c2v[RR];
            { float c2 = fast_sigmoid(gf.x)*scc[0][u] + fast_sigmoid(gi.x)*fast_tanh(gg.x);
              h2v[0]=fast_sigmoid(go.x)*fast_tanh(c2); c2v[0]=c2; }
            { float c2 = fast_sigmoid(gf.y)*scc[1][u] + fast_sigmoid(gi.y)*fast_tanh(gg.y);
              h2v[1]=fast_sigmoid(go.y)*fast_tanh(c2); c2v[1]=c2; }
            { float c2 = fast_sigmoid(gf.z)*scc[2][u] + fast_sigmoid(gi.z)*fast_tanh(gg.z);
              h2v[2]=fast_sigmoid(go.z)*fast_tanh(c2); c2v[2]=c2; }
            { float c2 = fast_sigmoid(gf.w)*scc[3][u] + fast_sigmoid(gi.w)*fast_tanh(gg.w);
              h2v[3]=fast_sigmoid(go.w)*fast_tanh(c2); c2v[3]=c2; }
            u32 ph[RR], pc[RR];
            #pragma unroll
            for (int r=0;r<RR;r++){
                sh[r][u]=h2v[r]; scc[r][u]=c2v[r];
                float hn = __shfl_xor(h2v[r],1);
                float cn = __shfl_xor(c2v[r],1);
                ph[r] = packh2(h2v[r], hn);
                pc[r] = packh2(c2v[r], cn);
            }
            if (!(u&1)){
                uint4* x4 = (uint4*)sxT;
                x4[u>>1]        = make_uint4(ph[0],ph[1],ph[2],ph[3]);
                x4[64 + (u>>1)] = make_uint4(pc[0],pc[1],pc[2],pc[3]);
            }
        }
        __syncthreads();
    }
    if (tid < RR*HD){ int r=tid>>7,u=tid&127; dout[((size_t)g*RR + r) & 127] = sh[r][u]; } // keep live
}

// ---------------- diagnostic: sync-only (store + poll + 2 barriers) ----------------
__global__ __launch_bounds__(NT,1) void k_diag_sync(u64* __restrict__ Ptv,
                                                    float* __restrict__ dout){
    __shared__ float sy1[RR];
    const int tid = threadIdx.x, g = blockIdx.x;
    float acc = 0.f;
    for (int it=0; it<REP*TT; it++){
        u64* Pcur = Ptv + (size_t)(it&1)*BB*NB;
        const u32 tag = (u32)(it+1);
        __syncthreads();
        if (tid<128){
            float val = (float)(g+1)*1e-4f + (float)tid*1e-6f;
            u64 pk = ((u64)tag<<32) | (u64)__float_as_uint(val);
            __hip_atomic_store(&Pcur[(size_t)tid*NB + g], pk,
                               __ATOMIC_RELAXED, __HIP_MEMORY_SCOPE_AGENT);
            const int r = tid>>5, gp = tid&31;
            const u64* slot = &Pcur[(size_t)(RR*g+r)*NB + gp];
            u64 v;
            for(;;){
                v = __hip_atomic_load(slot, __ATOMIC_RELAXED, __HIP_MEMORY_SCOPE_AGENT);
                if (__all((u32)(v>>32)==tag)) break;
            }
            float s = __uint_as_float((u32)v);
            s += __shfl_xor(s,16); s += __shfl_xor(s,8); s += __shfl_xor(s,4);
            s += __shfl_xor(s,2);  s += __shfl_xor(s,1);
            if (gp==0) sy1[r] = s;
        }
        __syncthreads();
        acc += sy1[tid&3];
    }
    if (tid<RR) dout[g*RR+tid] = acc;
}

// ---------------- launcher ----------------
extern "C" void kernel_launch(void* const* d_in, const int* in_sizes, int n_in,
                              void* d_out, int out_size, void* d_ws, size_t ws_size,
                              hipStream_t stream){
    const float* Xe  = (const float*)d_in[0];
    const float* Xt  = (const float*)d_in[1];
    const float* W1  = (const float*)d_in[2];
    const float* b1  = (const float*)d_in[3];
    const float* W2  = (const float*)d_in[4];
    const float* b2  = (const float*)d_in[5];
    const float* Wfc = (const float*)d_in[6];
    const float* bfc = (const float*)d_in[7];
    const float* Wih = (const float*)d_in[8];
    const float* bih = (const float*)d_in[9];
    const float* Whh = (const float*)d_in[10];
    const float* bhh = (const float*)d_in[11];
    const float* Wfin= (const float*)d_in[12];
    const float* bfin= (const float*)d_in[13];

    u32* preE2 = (u32*)d_ws;                         // 8192*64 u32 = 2 MB
    u32* W1T   = preE2 + (size_t)8192*64;            // 16384 u32
    u32* WhhPT = W1T + 16384;                        // 32768 u32
    float* xtwT = (float*)(WhhPT + 32768);           // 8192 f
    u64* PtvA  = (u64*)(xtwT + 8192);                // 2*128*32 u64 (64 KB)
    u64* PtvB  = PtvA + (size_t)2*BB*NB;             // 64 KB
    float* dcomp = (float*)(PtvB + (size_t)2*BB*NB); // 128 f
    float* dsync = dcomp + 128;                      // 128 f
    float* outp  = (float*)d_out;

    const size_t dynLds = (size_t)32768*sizeof(u32); // 128 KB
    (void)hipFuncSetAttribute((const void*)k_loop,
        hipFuncAttributeMaxDynamicSharedMemorySize, (int)dynLds);
    (void)hipFuncSetAttribute((const void*)k_diag_comp,
        hipFuncAttributeMaxDynamicSharedMemorySize, (int)dynLds);

    hipLaunchKernelGGL(k_pre,  dim3(256), dim3(256), 0, stream, Xe, W1, b1, preE2);
    hipLaunchKernelGGL(k_pack, dim3(64),  dim3(256), 0, stream, W1, Whh, W1T, WhhPT);
    hipLaunchKernelGGL(k_xtw,  dim3(TT),  dim3(128), 0, stream, Xt, Wfc, bfc, xtwT);
    hipLaunchKernelGGL(k_loop, dim3(NB),  dim3(NT),  dynLds, stream,
        Xe, preE2, W1T, WhhPT, W2, b2, Wfc, Wih, bih, bhh, Wfin, bfin,
        xtwT, PtvA, outp);
    hipLaunchKernelGGL(k_diag_comp, dim3(NB), dim3(NT), dynLds, stream,
        Xe, preE2, W1T, WhhPT, W2, b2, Wfc, Wih, bih, bhh, xtwT, dcomp);
    hipLaunchKernelGGL(k_diag_sync, dim3(NB), dim3(NT), 0, stream, PtvB, dsync);
}